// Round 1
// baseline (107.695 us; speedup 1.0000x reference)
//
#include <hip/hip_runtime.h>

#define CROP_H 14
#define CROP_W 14
#define IMG_H 100
#define IMG_W 100
#define NCH 256

// Output: (N=512, C=256, 14, 14) fp32.
// Grid: (196, 512). blockIdx.y = box n (uniform per block).
// blockIdx.x * 256 + tid indexes c*196 + h*14 + w  (196*256/256 = 196 blocks).
__global__ __launch_bounds__(256) void crop_resize_kernel(
    const float* __restrict__ image,   // (8, 256, 100, 100)
    const float* __restrict__ boxes,   // (512, 4)
    const int*   __restrict__ box_ind, // (512,)
    float* __restrict__ out)           // (512, 256, 14, 14)
{
    const int n = blockIdx.y;
    const int i = blockIdx.x * 256 + threadIdx.x;   // 0 .. 50175
    const int c  = i / (CROP_H * CROP_W);
    const int hw = i - c * (CROP_H * CROP_W);
    const int h  = hw / CROP_W;
    const int w  = hw - h * CROP_W;

    // box params (uniform per block -> scalar loads)
    const float y1 = boxes[n * 4 + 0];
    const float x1 = boxes[n * 4 + 1];
    const float y2 = boxes[n * 4 + 2];
    const float x2 = boxes[n * 4 + 3];
    const int   b  = box_ind[n];

    const float scale_y = (y2 - y1) * (float)(IMG_H - 1) / (float)(CROP_H - 1);
    const float scale_x = (x2 - x1) * (float)(IMG_W - 1) / (float)(CROP_W - 1);

    const float in_y = y1 * (float)(IMG_H - 1) + (float)h * scale_y;
    const float in_x = x1 * (float)(IMG_W - 1) + (float)w * scale_x;

    const bool valid = (in_y >= 0.0f) & (in_y <= (float)(IMG_H - 1)) &
                       (in_x >= 0.0f) & (in_x <= (float)(IMG_W - 1));

    const float yc = fminf(fmaxf(in_y, 0.0f), (float)(IMG_H - 1));
    const float xc = fminf(fmaxf(in_x, 0.0f), (float)(IMG_W - 1));

    const float y0f = floorf(yc);
    const float x0f = floorf(xc);
    const float ly = yc - y0f;
    const float lx = xc - x0f;

    const int y0 = (int)y0f;
    const int x0 = (int)x0f;
    const int y1i = min(y0 + 1, IMG_H - 1);
    const int x1i = min(x0 + 1, IMG_W - 1);

    const float* __restrict__ p =
        image + ((size_t)(b * NCH + c)) * (IMG_H * IMG_W);

    const float tl = p[y0  * IMG_W + x0];
    const float tr = p[y0  * IMG_W + x1i];
    const float bl = p[y1i * IMG_W + x0];
    const float br = p[y1i * IMG_W + x1i];

    const float top = tl + (tr - tl) * lx;
    const float bot = bl + (br - bl) * lx;
    float val = top + (bot - top) * ly;
    val = valid ? val : 0.0f;

    out[(size_t)n * (NCH * CROP_H * CROP_W) + i] = val;
}

extern "C" void kernel_launch(void* const* d_in, const int* in_sizes, int n_in,
                              void* d_out, int out_size, void* d_ws, size_t ws_size,
                              hipStream_t stream) {
    const float* image   = (const float*)d_in[0];
    const float* boxes   = (const float*)d_in[1];
    const int*   box_ind = (const int*)d_in[2];
    float* out = (float*)d_out;

    dim3 grid(196, 512);
    dim3 block(256);
    crop_resize_kernel<<<grid, block, 0, stream>>>(image, boxes, box_ind, out);
}

// Round 2
// 104.158 us; speedup vs baseline: 1.0340x; 1.0340x over previous
//
#include <hip/hip_runtime.h>

#define CROP_H 14
#define CROP_W 14
#define CROP_HW 196
#define IMG_H 100
#define IMG_W 100
#define PLANE 10000
#define NCH 256

// Grid: (4, 512). blockIdx.y = box n; blockIdx.x = 64-channel slab.
// Phase 1: threads 0..195 compute tap offsets + weights for each (h,w) into LDS.
// Phase 2: each thread emits 49 outputs (idx = iter*256 + tid over 64ch x 196hw),
//          fully coalesced stores, per-output work = LDS read + 4 taps + interp.
__global__ __launch_bounds__(256) void crop_resize_kernel(
    const float* __restrict__ image,   // (8, 256, 100, 100)
    const float* __restrict__ boxes,   // (512, 4)
    const int*   __restrict__ box_ind, // (512,)
    float* __restrict__ out)           // (512, 256, 14, 14)
{
    __shared__ int4   s_ofs[CROP_HW];  // tl, tr, bl, br plane offsets
    __shared__ float4 s_w[CROP_HW];    // lx, ly, validmask, pad

    const int n = blockIdx.y;
    const int t = threadIdx.x;

    if (t < CROP_HW) {
        const int h = t / CROP_W;
        const int w = t - h * CROP_W;

        const float4 bx = reinterpret_cast<const float4*>(boxes)[n];
        const float y1 = bx.x, x1 = bx.y, y2 = bx.z, x2 = bx.w;

        const float scale_y = (y2 - y1) * (float)(IMG_H - 1) / (float)(CROP_H - 1);
        const float scale_x = (x2 - x1) * (float)(IMG_W - 1) / (float)(CROP_W - 1);

        const float in_y = y1 * (float)(IMG_H - 1) + (float)h * scale_y;
        const float in_x = x1 * (float)(IMG_W - 1) + (float)w * scale_x;

        const bool valid = (in_y >= 0.0f) & (in_y <= (float)(IMG_H - 1)) &
                           (in_x >= 0.0f) & (in_x <= (float)(IMG_W - 1));

        const float yc = fminf(fmaxf(in_y, 0.0f), (float)(IMG_H - 1));
        const float xc = fminf(fmaxf(in_x, 0.0f), (float)(IMG_W - 1));

        const float y0f = floorf(yc);
        const float x0f = floorf(xc);
        const float ly = yc - y0f;
        const float lx = xc - x0f;

        const int y0  = (int)y0f;
        const int x0  = (int)x0f;
        const int y1i = min(y0 + 1, IMG_H - 1);
        const int x1i = min(x0 + 1, IMG_W - 1);

        s_ofs[t] = make_int4(y0 * IMG_W + x0, y0 * IMG_W + x1i,
                             y1i * IMG_W + x0, y1i * IMG_W + x1i);
        s_w[t] = make_float4(lx, ly, valid ? 1.0f : 0.0f, 0.0f);
    }
    __syncthreads();

    const int b = box_ind[n];
    const float* __restrict__ imgb = image + (size_t)b * (NCH * PLANE)
                                           + (size_t)(blockIdx.x * 64) * PLANE;
    float* __restrict__ outp = out + (size_t)n * (NCH * CROP_HW)
                                   + (size_t)(blockIdx.x * 64) * CROP_HW;

    #pragma unroll 7
    for (int iter = 0; iter < 49; ++iter) {
        const int idx = iter * 256 + t;        // 0 .. 12543 within the slab
        const int cl  = idx / CROP_HW;         // 0 .. 63
        const int hw  = idx - cl * CROP_HW;    // 0 .. 195

        const int4   o  = s_ofs[hw];
        const float4 wv = s_w[hw];

        const float* __restrict__ p = imgb + (size_t)cl * PLANE;
        const float tl = p[o.x];
        const float tr = p[o.y];
        const float bl = p[o.z];
        const float br = p[o.w];

        const float top = tl + (tr - tl) * wv.x;
        const float bot = bl + (br - bl) * wv.x;
        float val = top + (bot - top) * wv.y;

        outp[idx] = val * wv.z;
    }
}

extern "C" void kernel_launch(void* const* d_in, const int* in_sizes, int n_in,
                              void* d_out, int out_size, void* d_ws, size_t ws_size,
                              hipStream_t stream) {
    const float* image   = (const float*)d_in[0];
    const float* boxes   = (const float*)d_in[1];
    const int*   box_ind = (const int*)d_in[2];
    float* out = (float*)d_out;

    dim3 grid(4, 512);
    dim3 block(256);
    crop_resize_kernel<<<grid, block, 0, stream>>>(image, boxes, box_ind, out);
}

// Round 3
// 57.131 us; speedup vs baseline: 1.8850x; 1.8231x over previous
//
#include <hip/hip_runtime.h>

#define CROP_H 14
#define CROP_W 14
#define CROP_HW 196
#define IMG_H 100
#define IMG_W 100
#define PLANE 10000
#define NCH 256
#define NBOX 512
#define NIMG 8

// ---------------- Kernel 1: per-(box, hw) geometry precompute -> d_ws ----------------
// geo[n*196+hw] = float4{ bits: ofs_tl | dx<<16 | dy<<17 , lx, ly, validmask }
__global__ __launch_bounds__(256) void geom_kernel(
    const float* __restrict__ boxes, float4* __restrict__ geo)
{
    const int n = blockIdx.x;
    const int t = threadIdx.x;
    if (t >= CROP_HW) return;
    const int h = t / CROP_W;
    const int w = t - h * CROP_W;

    const float4 bx = reinterpret_cast<const float4*>(boxes)[n];
    const float y1 = bx.x, x1 = bx.y, y2 = bx.z, x2 = bx.w;

    const float scale_y = (y2 - y1) * (float)(IMG_H - 1) / (float)(CROP_H - 1);
    const float scale_x = (x2 - x1) * (float)(IMG_W - 1) / (float)(CROP_W - 1);

    const float in_y = y1 * (float)(IMG_H - 1) + (float)h * scale_y;
    const float in_x = x1 * (float)(IMG_W - 1) + (float)w * scale_x;

    const bool valid = (in_y >= 0.0f) & (in_y <= (float)(IMG_H - 1)) &
                       (in_x >= 0.0f) & (in_x <= (float)(IMG_W - 1));

    const float yc = fminf(fmaxf(in_y, 0.0f), (float)(IMG_H - 1));
    const float xc = fminf(fmaxf(in_x, 0.0f), (float)(IMG_W - 1));

    const float y0f = floorf(yc);
    const float x0f = floorf(xc);
    const float ly = yc - y0f;
    const float lx = xc - x0f;

    const int y0  = (int)y0f;
    const int x0  = (int)x0f;
    const int dy  = min(y0 + 1, IMG_H - 1) - y0;   // 0 or 1
    const int dx  = min(x0 + 1, IMG_W - 1) - x0;   // 0 or 1

    const int pk = (y0 * IMG_W + x0) | (dx << 16) | (dy << 17);

    float4 g;
    g.x = __int_as_float(pk);
    g.y = lx;
    g.z = ly;
    g.w = valid ? 1.0f : 0.0f;
    geo[n * CROP_HW + t] = g;
}

// ---------------- Kernel 2: one block per (b, c) plane ----------------
// Stage plane in LDS (streaming read, exactly once), gather taps from LDS for
// every box with box_ind==b.
__global__ __launch_bounds__(256) void crop_resize_main(
    const float* __restrict__ image,    // (8, 256, 100, 100)
    const int*   __restrict__ box_ind,  // (512,)
    const float4* __restrict__ geo,     // (512, 196)
    float* __restrict__ out)            // (512, 256, 14, 14)
{
    __shared__ float s_plane[PLANE];
    __shared__ int   s_list[NBOX];
    __shared__ int   s_nb;

    const int blk = blockIdx.x;
    const int b   = blk >> 8;        // 0..7
    const int c   = blk & 255;       // 0..255
    const int t   = threadIdx.x;

    // ---- wave 0: build stable compacted list of boxes with box_ind==b ----
    if (t < 64) {
        int nb = 0;
        for (int k = 0; k < NBOX / 64; ++k) {
            const int n = k * 64 + t;
            const bool m = (box_ind[n] == b);
            const unsigned long long mask = __ballot(m);
            if (m) {
                const int pos = nb + __popcll(mask & ((1ull << t) - 1ull));
                s_list[pos] = n;
            }
            nb += __popcll(mask);
        }
        if (t == 0) s_nb = nb;
    }

    // ---- all threads: stage the (b,c) plane into LDS (streaming float4) ----
    const float4* __restrict__ plane_g =
        reinterpret_cast<const float4*>(image + ((size_t)(b * NCH + c)) * PLANE);
    float4* __restrict__ s_plane4 = reinterpret_cast<float4*>(s_plane);
    #pragma unroll
    for (int i = t; i < PLANE / 4; i += 256) {
        s_plane4[i] = plane_g[i];
    }
    __syncthreads();

    const int total = s_nb * CROP_HW;
    const size_t out_c = (size_t)c * CROP_HW;

    #pragma unroll 4
    for (int idx = t; idx < total; idx += 256) {
        const int bl = idx / CROP_HW;          // box slot in list
        const int hw = idx - bl * CROP_HW;
        const int n  = s_list[bl];

        const float4 g = geo[(size_t)n * CROP_HW + hw];
        const int pk  = __float_as_int(g.x);
        const int o   = pk & 0x3FFF;
        const int dx  = (pk >> 16) & 1;
        const int dyo = ((pk >> 17) & 1) * IMG_W;

        const float tl = s_plane[o];
        const float tr = s_plane[o + dx];
        const float bl2 = s_plane[o + dyo];
        const float br = s_plane[o + dyo + dx];

        const float top = tl + (tr - tl) * g.y;
        const float bot = bl2 + (br - bl2) * g.y;
        const float val = (top + (bot - top) * g.z) * g.w;

        out[(size_t)n * (NCH * CROP_HW) + out_c + hw] = val;
    }
}

// ---------------- Fallback (ws too small): round-1 kernel, known-good ----------------
__global__ __launch_bounds__(256) void crop_resize_simple(
    const float* __restrict__ image, const float* __restrict__ boxes,
    const int* __restrict__ box_ind, float* __restrict__ out)
{
    const int n = blockIdx.y;
    const int i = blockIdx.x * 256 + threadIdx.x;
    const int c  = i / CROP_HW;
    const int hw = i - c * CROP_HW;
    const int h  = hw / CROP_W;
    const int w  = hw - h * CROP_W;

    const float y1 = boxes[n * 4 + 0];
    const float x1 = boxes[n * 4 + 1];
    const float y2 = boxes[n * 4 + 2];
    const float x2 = boxes[n * 4 + 3];
    const int   b  = box_ind[n];

    const float scale_y = (y2 - y1) * (float)(IMG_H - 1) / (float)(CROP_H - 1);
    const float scale_x = (x2 - x1) * (float)(IMG_W - 1) / (float)(CROP_W - 1);
    const float in_y = y1 * (float)(IMG_H - 1) + (float)h * scale_y;
    const float in_x = x1 * (float)(IMG_W - 1) + (float)w * scale_x;
    const bool valid = (in_y >= 0.0f) & (in_y <= (float)(IMG_H - 1)) &
                       (in_x >= 0.0f) & (in_x <= (float)(IMG_W - 1));
    const float yc = fminf(fmaxf(in_y, 0.0f), (float)(IMG_H - 1));
    const float xc = fminf(fmaxf(in_x, 0.0f), (float)(IMG_W - 1));
    const float y0f = floorf(yc), x0f = floorf(xc);
    const float ly = yc - y0f, lx = xc - x0f;
    const int y0 = (int)y0f, x0 = (int)x0f;
    const int y1i = min(y0 + 1, IMG_H - 1), x1i = min(x0 + 1, IMG_W - 1);

    const float* __restrict__ p = image + ((size_t)(b * NCH + c)) * PLANE;
    const float tl = p[y0  * IMG_W + x0];
    const float tr = p[y0  * IMG_W + x1i];
    const float bl = p[y1i * IMG_W + x0];
    const float br = p[y1i * IMG_W + x1i];
    const float top = tl + (tr - tl) * lx;
    const float bot = bl + (br - bl) * lx;
    float val = top + (bot - top) * ly;
    out[(size_t)n * (NCH * CROP_HW) + i] = valid ? val : 0.0f;
}

extern "C" void kernel_launch(void* const* d_in, const int* in_sizes, int n_in,
                              void* d_out, int out_size, void* d_ws, size_t ws_size,
                              hipStream_t stream) {
    const float* image   = (const float*)d_in[0];
    const float* boxes   = (const float*)d_in[1];
    const int*   box_ind = (const int*)d_in[2];
    float* out = (float*)d_out;

    const size_t geo_bytes = (size_t)NBOX * CROP_HW * sizeof(float4);
    if (ws_size < geo_bytes) {
        dim3 grid(196, NBOX);
        crop_resize_simple<<<grid, dim3(256), 0, stream>>>(image, boxes, box_ind, out);
        return;
    }

    float4* geo = (float4*)d_ws;
    geom_kernel<<<dim3(NBOX), dim3(256), 0, stream>>>(boxes, geo);
    crop_resize_main<<<dim3(NIMG * NCH), dim3(256), 0, stream>>>(image, box_ind, geo, out);
}

// Round 4
// 51.749 us; speedup vs baseline: 2.0811x; 1.1040x over previous
//
#include <hip/hip_runtime.h>
#include <hip/hip_fp16.h>

#define CROP_H 14
#define CROP_W 14
#define CROP_HW 196
#define IMG_H 100
#define IMG_W 100
#define PLANE 10000
#define NCH 256
#define NBOX 512
#define NIMG 8

// d_ws layout:
//   geo   : uint2[NBOX*CROP_HW]   (8 B per (n,hw))           @ 0
//   perm  : int[NBOX]                                        @ GEO_BYTES
//   starts: int[NIMG+1]                                      @ GEO_BYTES + NBOX*4
#define GEO_BYTES ((size_t)NBOX * CROP_HW * 8)
#define WS_NEED   (GEO_BYTES + NBOX * 4 + (NIMG + 1) * 4)

// ---------------- Kernel 1: geometry (blocks 0..511) + perm/starts (block 512) ----
__global__ __launch_bounds__(256) void setup_kernel(
    const float* __restrict__ boxes, const int* __restrict__ box_ind,
    uint2* __restrict__ geo, int* __restrict__ perm, int* __restrict__ starts)
{
    const int blk = blockIdx.x;
    const int t = threadIdx.x;

    if (blk == NBOX) {
        // one wave builds a stable bucketed permutation of boxes by image index
        if (t < 64) {
            int base = 0;
            for (int b = 0; b < NIMG; ++b) {
                if (t == 0) starts[b] = base;
                int nb = 0;
                for (int k = 0; k < NBOX / 64; ++k) {
                    const int n = k * 64 + t;
                    const bool m = (box_ind[n] == b);
                    const unsigned long long mask = __ballot(m);
                    if (m) perm[base + nb + __popcll(mask & ((1ull << t) - 1ull))] = n;
                    nb += __popcll(mask);
                }
                base += nb;   // uniform across lanes
            }
            if (t == 0) starts[NIMG] = base;
        }
        return;
    }

    if (t >= CROP_HW) return;
    const int n = blk;
    const int h = t / CROP_W;
    const int w = t - h * CROP_W;

    const float4 bx = reinterpret_cast<const float4*>(boxes)[n];
    const float y1 = bx.x, x1 = bx.y, y2 = bx.z, x2 = bx.w;

    const float scale_y = (y2 - y1) * (float)(IMG_H - 1) / (float)(CROP_H - 1);
    const float scale_x = (x2 - x1) * (float)(IMG_W - 1) / (float)(CROP_W - 1);

    const float in_y = y1 * (float)(IMG_H - 1) + (float)h * scale_y;
    const float in_x = x1 * (float)(IMG_W - 1) + (float)w * scale_x;

    const bool valid = (in_y >= 0.0f) & (in_y <= (float)(IMG_H - 1)) &
                       (in_x >= 0.0f) & (in_x <= (float)(IMG_W - 1));

    const float yc = fminf(fmaxf(in_y, 0.0f), (float)(IMG_H - 1));
    const float xc = fminf(fmaxf(in_x, 0.0f), (float)(IMG_W - 1));

    const float y0f = floorf(yc);
    const float x0f = floorf(xc);
    const float ly = yc - y0f;
    const float lx = xc - x0f;

    const int y0  = (int)y0f;
    const int x0  = (int)x0f;
    const int dy  = min(y0 + 1, IMG_H - 1) - y0;   // 0/1
    const int dx  = min(x0 + 1, IMG_W - 1) - x0;   // 0/1

    unsigned pk = (unsigned)(y0 * IMG_W + x0) | ((unsigned)dx << 16)
                | ((unsigned)dy << 17) | (valid ? (1u << 18) : 0u);

    const __half2 hh = __floats2half2_rn(lx, ly);
    const unsigned hbits = *reinterpret_cast<const unsigned*>(&hh);

    geo[n * CROP_HW + t] = make_uint2(pk, hbits);
}

// ---------------- bilinear from LDS plane, packed geometry ----------------
__device__ __forceinline__ float bilerp(const float* __restrict__ s,
                                        unsigned pk, unsigned hbits)
{
    const int o   = (int)(pk & 0x3FFFu);
    const int dx  = (int)((pk >> 16) & 1u);
    const int dyo = (int)((pk >> 17) & 1u) * IMG_W;
    const __half2 h = *reinterpret_cast<const __half2*>(&hbits);
    const float lx = __low2float(h);
    const float ly = __high2float(h);
    const float wm = (pk & (1u << 18)) ? 1.0f : 0.0f;

    const float tl = s[o];
    const float tr = s[o + dx];
    const float bl = s[o + dyo];
    const float br = s[o + dyo + dx];

    const float top = tl + (tr - tl) * lx;
    const float bot = bl + (br - bl) * lx;
    return (top + (bot - top) * ly) * wm;
}

// ---------------- Kernel 2: one block per (b, c) plane ----------------
__global__ __launch_bounds__(256, 4) void crop_resize_main(
    const float* __restrict__ image,    // (8, 256, 100, 100)
    const int*   __restrict__ perm,     // sorted-by-b box ids
    const int*   __restrict__ starts,   // [9]
    const uint2* __restrict__ geo,      // (512, 196) packed
    float* __restrict__ out)            // (512, 256, 14, 14)
{
    __shared__ float s_plane[PLANE];    // 40000 B -> 4 blocks/CU

    const int blk = blockIdx.x;
    const int b   = blk >> 8;
    const int c   = blk & 255;
    const int t   = threadIdx.x;

    const int sb = starts[b];
    const int nb = starts[b + 1] - sb;

    const float4* __restrict__ plane_g =
        reinterpret_cast<const float4*>(image + ((size_t)(b * NCH + c)) * PLANE);
    float4* __restrict__ s4 = reinterpret_cast<float4*>(s_plane);
    #pragma unroll
    for (int i = t; i < PLANE / 4; i += 256) s4[i] = plane_g[i];
    __syncthreads();

    const int total = nb * CROP_HW;     // even
    const uint4* __restrict__ geo4 = reinterpret_cast<const uint4*>(geo);
    float* __restrict__ outc = out + (size_t)c * CROP_HW;

    #pragma unroll 2
    for (int idx = 2 * t; idx < total; idx += 512) {
        const int bl = idx / CROP_HW;          // magic-mul
        const int hw = idx - bl * CROP_HW;     // even, <= 194
        const int n  = perm[sb + bl];

        const uint4 g = geo4[(n * CROP_HW + hw) >> 1];   // 2 packed entries

        const float v0 = bilerp(s_plane, g.x, g.y);
        const float v1 = bilerp(s_plane, g.z, g.w);

        *reinterpret_cast<float2*>(outc + (size_t)n * (NCH * CROP_HW) + hw) =
            make_float2(v0, v1);
    }
}

// ---------------- Fallback (ws too small): known-good direct kernel ----------------
__global__ __launch_bounds__(256) void crop_resize_simple(
    const float* __restrict__ image, const float* __restrict__ boxes,
    const int* __restrict__ box_ind, float* __restrict__ out)
{
    const int n = blockIdx.y;
    const int i = blockIdx.x * 256 + threadIdx.x;
    const int c  = i / CROP_HW;
    const int hw = i - c * CROP_HW;
    const int h  = hw / CROP_W;
    const int w  = hw - h * CROP_W;

    const float y1 = boxes[n * 4 + 0];
    const float x1 = boxes[n * 4 + 1];
    const float y2 = boxes[n * 4 + 2];
    const float x2 = boxes[n * 4 + 3];
    const int   b  = box_ind[n];

    const float scale_y = (y2 - y1) * (float)(IMG_H - 1) / (float)(CROP_H - 1);
    const float scale_x = (x2 - x1) * (float)(IMG_W - 1) / (float)(CROP_W - 1);
    const float in_y = y1 * (float)(IMG_H - 1) + (float)h * scale_y;
    const float in_x = x1 * (float)(IMG_W - 1) + (float)w * scale_x;
    const bool valid = (in_y >= 0.0f) & (in_y <= (float)(IMG_H - 1)) &
                       (in_x >= 0.0f) & (in_x <= (float)(IMG_W - 1));
    const float yc = fminf(fmaxf(in_y, 0.0f), (float)(IMG_H - 1));
    const float xc = fminf(fmaxf(in_x, 0.0f), (float)(IMG_W - 1));
    const float y0f = floorf(yc), x0f = floorf(xc);
    const float ly = yc - y0f, lx = xc - x0f;
    const int y0 = (int)y0f, x0 = (int)x0f;
    const int y1i = min(y0 + 1, IMG_H - 1), x1i = min(x0 + 1, IMG_W - 1);

    const float* __restrict__ p = image + ((size_t)(b * NCH + c)) * PLANE;
    const float tl = p[y0  * IMG_W + x0];
    const float tr = p[y0  * IMG_W + x1i];
    const float bl = p[y1i * IMG_W + x0];
    const float br = p[y1i * IMG_W + x1i];
    const float top = tl + (tr - tl) * lx;
    const float bot = bl + (br - bl) * lx;
    float val = top + (bot - top) * ly;
    out[(size_t)n * (NCH * CROP_HW) + i] = valid ? val : 0.0f;
}

extern "C" void kernel_launch(void* const* d_in, const int* in_sizes, int n_in,
                              void* d_out, int out_size, void* d_ws, size_t ws_size,
                              hipStream_t stream) {
    const float* image   = (const float*)d_in[0];
    const float* boxes   = (const float*)d_in[1];
    const int*   box_ind = (const int*)d_in[2];
    float* out = (float*)d_out;

    if (ws_size < WS_NEED) {
        dim3 grid(196, NBOX);
        crop_resize_simple<<<grid, dim3(256), 0, stream>>>(image, boxes, box_ind, out);
        return;
    }

    uint2* geo   = (uint2*)d_ws;
    int*   perm  = (int*)((char*)d_ws + GEO_BYTES);
    int*   starts = perm + NBOX;

    setup_kernel<<<dim3(NBOX + 1), dim3(256), 0, stream>>>(boxes, box_ind, geo, perm, starts);
    crop_resize_main<<<dim3(NIMG * NCH), dim3(256), 0, stream>>>(image, perm, starts, geo, out);
}